// Round 8
// baseline (553.961 us; speedup 1.0000x reference)
//
#include <hip/hip_runtime.h>
#include <hip/hip_bf16.h>
#include <cstdint>
#include <cstddef>

#define KDIM 4096   // IN_F
#define NDIM 4096   // OUT_F

typedef __attribute__((ext_vector_type(8))) short short8;
typedef __attribute__((ext_vector_type(8))) __bf16 bf16x8;
typedef __attribute__((ext_vector_type(4))) float f32x4;

// f32 -> bf16, round-to-nearest-even
__device__ __forceinline__ unsigned short bf16_rne(float f) {
    unsigned int u = __builtin_bit_cast(unsigned int, f);
    u += 0x7fffu + ((u >> 16) & 1u);
    return (unsigned short)(u >> 16);
}

__device__ __forceinline__ void gload_lds16(const unsigned short* g, unsigned short* l) {
    __builtin_amdgcn_global_load_lds(
        (const __attribute__((address_space(1))) unsigned int*)g,
        (__attribute__((address_space(3))) unsigned int*)l,
        16, 0, 0);
}

// ---------------- preprocess: x fp32 -> bf16 ----------------
__global__ void cvt_x_kernel(const float* __restrict__ x, unsigned short* __restrict__ xb) {
    long i = (long)blockIdx.x * blockDim.x + threadIdx.x;   // one thread = 8 elems
    float4 a = ((const float4*)x)[2 * i];
    float4 b = ((const float4*)x)[2 * i + 1];
    union { unsigned short u[8]; short8 v; } r;
    r.u[0] = bf16_rne(a.x); r.u[1] = bf16_rne(a.y);
    r.u[2] = bf16_rne(a.z); r.u[3] = bf16_rne(a.w);
    r.u[4] = bf16_rne(b.x); r.u[5] = bf16_rne(b.y);
    r.u[6] = bf16_rne(b.z); r.u[7] = bf16_rne(b.w);
    ((short8*)xb)[i] = r.v;
}

// ---------------- preprocess: dequant 2-bit W -> bf16 [N][K] ----------------
__global__ void dequant_w_kernel(const int* __restrict__ wp,
                                 const float* __restrict__ scales,
                                 const float* __restrict__ zeros,
                                 unsigned short* __restrict__ wb) {
    long i = (long)blockIdx.x * blockDim.x + threadIdx.x;   // one thread = 2 packed ints = 8 weights
    int2 p = ((const int2*)wp)[i];
    long base = i * 8;                    // flat weight index (o*4096 + k)
    int o = (int)(base >> 12);
    int g = (int)((base & 4095) >> 7);    // all 8 weights in same group (8 | 128)
    float s = scales[o * 32 + g];
    float z = zeros[o * 32 + g];
    union { unsigned short u[8]; short8 v; } r;
#pragma unroll
    for (int j = 0; j < 4; ++j) {
        r.u[j]     = bf16_rne((float)((p.x >> (2 * j)) & 3) * s + z);
        r.u[4 + j] = bf16_rne((float)((p.y >> (2 * j)) & 3) * s + z);
    }
    ((short8*)wb)[i] = r.v;
}

// ---------------- 256x256 8-phase GEMM with READ-AHEAD-1 ----------------
// C[M][N] = A[M][K](bf16) * B[N][K](bf16)^T + bias.
// R8: R7 structure + reads shifted one phase early. Per phase:
//   {stage | [vmcnt(4)@P4,P8] | s_barrier | lgkmcnt(0)+SB |
//    reads(p+1) issue-only | SB | setprio1 | 16 MFMA | setprio0 | s_barrier}
// lgkmcnt(0) now waits on reads issued a FULL PHASE earlier (no stall);
// fresh reads drain in the LDS pipe UNDER the MFMA cluster.
//
// READ/USE MAP (iter i: tile e=2i buf0@0, o=2i+1 buf1@32768):
//  prologue/P8: aF<-A0, bQ0<-B0 of even tile; used P1(Q1),P2/P3.
//  P1: bQ1<-B1(e)   used P2(Q2),P4(Q4)     | stage A0(o)->buf1
//  P2: aG<-A1(e)    used P3(Q3),P4(Q4)     | stage A1(o)->buf1
//  P3: (no reads)                          | stage B0(e+2)->buf0
//  P4: aF<-A0(o), bQ0<-B0(o) [buf1 resident: vmcnt(4) leaves P3,P4] | stage B1(e+2)->buf0
//  P5: bQ1<-B1(o)                          | stage A0(e+2)->buf0
//  P6: aG<-A1(o)                           | stage A1(e+2)->buf0
//  P7: (no reads)                          | stage B0(o+2)->buf1
//  P8: aF<-A0(e+2), bQ0<-B0(e+2) [buf0 resident: vmcnt(4) leaves P7,P8] | stage B1(o+2)->buf1
// Register WAR per slot: write always after last use (aF:P2->P4, aG:P4->P6,
//  bQ0:P3->P4(wait,barrier), bQ1:P4->P5, all per-wave program order). OK.
// REGION W-A-R: each stage's region's last ds_read RETURNED before the
//  preceding barrier (consumer's lgkmcnt(0) precedes its MFMA precedes the
//  phase-end barrier; stage issues after that barrier). Verified per region.
// VMCNT: stages always 2 loads/phase; at P4/P8 outstanding=12, vmcnt(4)
//  leaves the 2 newest stages' 4 loads -> next tile fully resident + barrier.
// Tail: e2/o2 clamp to CURRENT tile -> byte-idempotent restage (same src,
//  same dest); P8's final reads are dead. Post-loop vmcnt(0)+lgkmcnt(0).
// Swizzle (proven, 0 conflicts): LDS(r,8j)=G(r,8*(j^(r&7))).

#define PH_BAR_WAIT \
    __builtin_amdgcn_s_barrier(); \
    asm volatile("s_waitcnt lgkmcnt(0)" ::: "memory"); \
    __builtin_amdgcn_sched_barrier(0);

#define PH_MFMA_BEGIN \
    __builtin_amdgcn_sched_barrier(0); \
    __builtin_amdgcn_s_setprio(1);

#define PH_END \
    __builtin_amdgcn_s_setprio(0); \
    __builtin_amdgcn_s_barrier();

#define VMCNT4 \
    __builtin_amdgcn_sched_barrier(0); \
    asm volatile("s_waitcnt vmcnt(4)" ::: "memory"); \
    __builtin_amdgcn_sched_barrier(0);

#define RD_A(arr, DOFF, mh) \
    _Pragma("unroll") \
    for (int mi_ = 0; mi_ < 4; ++mi_) { \
        arr[mi_][0] = *(const short8*)&sm[(DOFF) + aBase + ((mh)*4 + mi_) * 1024 + sw0]; \
        arr[mi_][1] = *(const short8*)&sm[(DOFF) + aBase + ((mh)*4 + mi_) * 1024 + sw1]; \
    }

#define RD_B(bx, DOFF, n0) \
    _Pragma("unroll") \
    for (int ni_ = 0; ni_ < 2; ++ni_) { \
        bx[ni_][0] = *(const short8*)&sm[(DOFF) + bBase + ((n0) + ni_) * 1024 + sw0]; \
        bx[ni_][1] = *(const short8*)&sm[(DOFF) + bBase + ((n0) + ni_) * 1024 + sw1]; \
    }

#define QUADX(af, bx, mh, nh) \
    _Pragma("unroll") \
    for (int s_ = 0; s_ < 2; ++s_) { \
      _Pragma("unroll") \
      for (int mi_ = 0; mi_ < 4; ++mi_) { \
        _Pragma("unroll") \
        for (int ni_ = 0; ni_ < 2; ++ni_) { \
          acc[(mh)*4+mi_][(nh)*2+ni_] = __builtin_amdgcn_mfma_f32_16x16x32_bf16( \
            __builtin_bit_cast(bf16x8, af[mi_][s_]), \
            __builtin_bit_cast(bf16x8, bx[ni_][s_]), \
            acc[(mh)*4+mi_][(nh)*2+ni_], 0, 0, 0); \
        } } }

__global__ __launch_bounds__(512, 2) void gemm256(const unsigned short* __restrict__ A,
                                                  const unsigned short* __restrict__ B,
                                                  const float* __restrict__ bias,
                                                  float* __restrict__ C) {
    __shared__ __align__(16) unsigned short sm[65536];   // 128 KiB

    const int tid = threadIdx.x;
    const int w64 = tid >> 6;
    const int lane = tid & 63;

    // T1: bijective XCD swizzle (gridDim.x % 8 == 0)
    const int nwg = gridDim.x;
    const int chunk = nwg >> 3;
    const int s_id = (blockIdx.x & 7) * chunk + (blockIdx.x >> 3);
    const int nm = nwg >> 4;              // M tiles (N tiles fixed at 16)
    const int bm = s_id % nm;
    const int bn = s_id / nm;
    const int row0 = bm * 256;
    const int col0 = bn * 256;

    const int wr = w64 >> 2;              // 0..1 (M half: 128 rows)
    const int wc = w64 & 3;               // 0..3 (N quarter: 64 cols)

    // ---- stage addressing (proven): row srow(+64,+128h), swizzled k
    const int srow = tid >> 3;                                  // 0..63
    const int swzk = 8 * ((tid & 7) ^ ((tid >> 3) & 7));        // pre-swizzled src elem
    const unsigned short* srcA = A + (size_t)(row0 + srow) * KDIM + swzk;
    const unsigned short* srcB = B + (size_t)(col0 + srow) * KDIM + swzk;

    // ---- frag addressing (proven, 0 conflicts)
    const int lr = lane & 15;
    const int lk4 = lane >> 4;
    const int l7 = lane & 7;
    const int sw0 = 8 * (((0 << 2) + lk4) ^ l7);
    const int sw1 = 8 * (((1 << 2) + lk4) ^ l7);
    const int aBase = (wr * 128 + lr) * 64;
    const int bBase = 16384 + (wc * 64 + lr) * 64;

    f32x4 acc[8][4] = {};
    short8 aF[4][2], aG[4][2], bQ0[2][2], bQ1[2][2];

    auto stageA = [&](int hh, int tile, int db) {
        const unsigned short* g = srcA + (size_t)hh * 128 * KDIM + (size_t)tile * 64;
        unsigned short* l = &sm[db * 32768 + hh * 8192 + w64 * 512];
        gload_lds16(g, l);
        gload_lds16(g + (size_t)64 * KDIM, l + 4096);
    };
    auto stageB = [&](int hh, int tile, int db) {
        const unsigned short* g = srcB + (size_t)hh * 128 * KDIM + (size_t)tile * 64;
        unsigned short* l = &sm[db * 32768 + 16384 + hh * 8192 + w64 * 512];
        gload_lds16(g, l);
        gload_lds16(g + (size_t)64 * KDIM, l + 4096);
    };

    const int NT = KDIM / 64;   // 64 K-tiles (even)

    // ---- prologue: tile0 -> buf0 (8 loads), tile1.B -> buf1 (4 loads)
    stageB(0, 0, 0); stageB(1, 0, 0); stageA(0, 0, 0); stageA(1, 0, 0);
    stageB(0, 1, 1); stageB(1, 1, 1);
    VMCNT4                      // buf0 fully resident; buf1.B still flying
    __builtin_amdgcn_s_barrier();
    RD_A(aF, 0, 0)              // iter -1 "P8 tail": reads for iter0 P1
    RD_B(bQ0, 0, 0)
    __builtin_amdgcn_sched_barrier(0);

    for (int i = 0; i < NT / 2; ++i) {
        const int e = 2 * i;
        const int o = e + 1;
        const int e2 = (e + 2 < NT) ? e + 2 : e;   // clamp: byte-idempotent restage
        const int o2 = (o + 2 < NT) ? o + 2 : o;

        // ===== P1: MFMA Q1(e); read B1(e); stage A0(o)->buf1 =====
        stageA(0, o, 1);
        PH_BAR_WAIT
        RD_B(bQ1, 0, 2)
        PH_MFMA_BEGIN
        QUADX(aF, bQ0, 0, 0)
        PH_END
        // ===== P2: MFMA Q2(e); read A1(e); stage A1(o)->buf1 =====
        stageA(1, o, 1);
        PH_BAR_WAIT
        RD_A(aG, 0, 1)
        PH_MFMA_BEGIN
        QUADX(aF, bQ1, 0, 1)
        PH_END
        // ===== P3: MFMA Q3(e); no reads; stage B0(e+2)->buf0 =====
        stageB(0, e2, 0);
        PH_BAR_WAIT
        PH_MFMA_BEGIN
        QUADX(aG, bQ0, 1, 0)
        PH_END
        // ===== P4: MFMA Q4(e); vmcnt=>buf1 resident; read A0(o),B0(o); stage B1(e+2)->buf0 =====
        stageB(1, e2, 0);
        VMCNT4
        PH_BAR_WAIT
        RD_A(aF, 32768, 0)
        RD_B(bQ0, 32768, 0)
        PH_MFMA_BEGIN
        QUADX(aG, bQ1, 1, 1)
        PH_END

        // ===== P5: MFMA Q1(o); read B1(o); stage A0(e+2)->buf0 =====
        stageA(0, e2, 0);
        PH_BAR_WAIT
        RD_B(bQ1, 32768, 2)
        PH_MFMA_BEGIN
        QUADX(aF, bQ0, 0, 0)
        PH_END
        // ===== P6: MFMA Q2(o); read A1(o); stage A1(e+2)->buf0 =====
        stageA(1, e2, 0);
        PH_BAR_WAIT
        RD_A(aG, 32768, 1)
        PH_MFMA_BEGIN
        QUADX(aF, bQ1, 0, 1)
        PH_END
        // ===== P7: MFMA Q3(o); no reads; stage B0(o+2)->buf1 =====
        stageB(0, o2, 1);
        PH_BAR_WAIT
        PH_MFMA_BEGIN
        QUADX(aG, bQ0, 1, 0)
        PH_END
        // ===== P8: MFMA Q4(o); vmcnt=>buf0(e+2) resident; read A0(e+2),B0(e+2); stage B1(o+2)->buf1 =====
        stageB(1, o2, 1);
        VMCNT4
        PH_BAR_WAIT
        RD_A(aF, 0, 0)
        RD_B(bQ0, 0, 0)
        PH_MFMA_BEGIN
        QUADX(aG, bQ1, 1, 1)
        PH_END
    }

    // no LDS-DMA / dangling reads may outlive the loop
    __builtin_amdgcn_sched_barrier(0);
    asm volatile("s_waitcnt vmcnt(0) lgkmcnt(0)" ::: "memory");
    __builtin_amdgcn_sched_barrier(0);

    // ---- epilogue: C/D layout col=lane&15, row=(lane>>4)*4+r
#pragma unroll
    for (int m = 0; m < 8; ++m) {
#pragma unroll
        for (int n = 0; n < 4; ++n) {
            int col = col0 + wc * 64 + n * 16 + lr;
            float bz = bias[col];
#pragma unroll
            for (int r = 0; r < 4; ++r) {
                int row = row0 + wr * 128 + m * 16 + lk4 * 4 + r;
                C[(size_t)row * NDIM + col] = acc[m][n][r] + bz;
            }
        }
    }
}

// ---------------- emergency fallback (ws too small / odd shape): exact fp32 ----------------
__global__ void fallback_kernel(const float* __restrict__ x, const int* __restrict__ wp,
                                const float* __restrict__ scales, const float* __restrict__ zeros,
                                const float* __restrict__ bias, float* __restrict__ out) {
    int o = blockIdx.x * 256 + threadIdx.x;
    int m = blockIdx.y;
    __shared__ float xs[KDIM];
    for (int i = threadIdx.x; i < KDIM; i += 256) xs[i] = x[(size_t)m * KDIM + i];
    __syncthreads();
    float acc = 0.f;
    for (int g = 0; g < 32; ++g) {
        float s = scales[o * 32 + g], z = zeros[o * 32 + g];
        float aq = 0.f, ax = 0.f;
        for (int j = 0; j < 32; ++j) {
            int p = wp[o * 1024 + g * 32 + j];
            int kb = g * 128 + j * 4;
#pragma unroll
            for (int q = 0; q < 4; ++q) {
                float xv = xs[kb + q];
                aq += xv * (float)((p >> (2 * q)) & 3);
                ax += xv;
            }
        }
        acc += s * aq + z * ax;
    }
    out[(size_t)m * NDIM + o] = acc + bias[o];
}

extern "C" void kernel_launch(void* const* d_in, const int* in_sizes, int n_in,
                              void* d_out, int out_size, void* d_ws, size_t ws_size,
                              hipStream_t stream) {
    const float* x      = (const float*)d_in[0];
    const int*   wp     = (const int*)d_in[1];
    const float* scales = (const float*)d_in[2];
    const float* zeros  = (const float*)d_in[3];
    const float* bias   = (const float*)d_in[4];
    float* out = (float*)d_out;

    const long M = (long)in_sizes[0] / KDIM;            // 8192
    const long PACKED = (long)in_sizes[1];              // 4194304
    const size_t need = (size_t)M * KDIM * 2 + (size_t)NDIM * KDIM * 2;  // 96 MB

    if (ws_size >= need && (M % 256) == 0) {
        unsigned short* xb = (unsigned short*)d_ws;
        unsigned short* wb = xb + (size_t)M * KDIM;
        cvt_x_kernel<<<(M * KDIM / 8) / 256, 256, 0, stream>>>(x, xb);
        dequant_w_kernel<<<(PACKED / 2) / 256, 256, 0, stream>>>(wp, scales, zeros, wb);
        int nwg = (int)(M / 256) * (NDIM / 256);        // 32*16 = 512, %8==0
        gemm256<<<nwg, 512, 0, stream>>>(xb, wb, bias, out);
    } else {
        dim3 grid(NDIM / 256, M);
        fallback_kernel<<<grid, 256, 0, stream>>>(x, wp, scales, zeros, bias, out);
    }
}

// Round 9
// 409.739 us; speedup vs baseline: 1.3520x; 1.3520x over previous
//
#include <hip/hip_runtime.h>
#include <hip/hip_bf16.h>
#include <cstdint>
#include <cstddef>

#define KDIM 4096   // IN_F
#define NDIM 4096   // OUT_F

typedef __attribute__((ext_vector_type(8))) short short8;
typedef __attribute__((ext_vector_type(8))) __bf16 bf16x8;
typedef __attribute__((ext_vector_type(4))) float f32x4;

// f32 -> bf16, round-to-nearest-even
__device__ __forceinline__ unsigned short bf16_rne(float f) {
    unsigned int u = __builtin_bit_cast(unsigned int, f);
    u += 0x7fffu + ((u >> 16) & 1u);
    return (unsigned short)(u >> 16);
}

__device__ __forceinline__ void gload_lds16(const unsigned short* g, unsigned short* l) {
    __builtin_amdgcn_global_load_lds(
        (const __attribute__((address_space(1))) unsigned int*)g,
        (__attribute__((address_space(3))) unsigned int*)l,
        16, 0, 0);
}

// ---------------- preprocess: x fp32 -> bf16 ----------------
__global__ void cvt_x_kernel(const float* __restrict__ x, unsigned short* __restrict__ xb) {
    long i = (long)blockIdx.x * blockDim.x + threadIdx.x;   // one thread = 8 elems
    float4 a = ((const float4*)x)[2 * i];
    float4 b = ((const float4*)x)[2 * i + 1];
    union { unsigned short u[8]; short8 v; } r;
    r.u[0] = bf16_rne(a.x); r.u[1] = bf16_rne(a.y);
    r.u[2] = bf16_rne(a.z); r.u[3] = bf16_rne(a.w);
    r.u[4] = bf16_rne(b.x); r.u[5] = bf16_rne(b.y);
    r.u[6] = bf16_rne(b.z); r.u[7] = bf16_rne(b.w);
    ((short8*)xb)[i] = r.v;
}

// ---------------- preprocess: dequant 2-bit W -> bf16 [N][K] ----------------
__global__ void dequant_w_kernel(const int* __restrict__ wp,
                                 const float* __restrict__ scales,
                                 const float* __restrict__ zeros,
                                 unsigned short* __restrict__ wb) {
    long i = (long)blockIdx.x * blockDim.x + threadIdx.x;   // one thread = 2 packed ints = 8 weights
    int2 p = ((const int2*)wp)[i];
    long base = i * 8;                    // flat weight index (o*4096 + k)
    int o = (int)(base >> 12);
    int g = (int)((base & 4095) >> 7);    // all 8 weights in same group (8 | 128)
    float s = scales[o * 32 + g];
    float z = zeros[o * 32 + g];
    union { unsigned short u[8]; short8 v; } r;
#pragma unroll
    for (int j = 0; j < 4; ++j) {
        r.u[j]     = bf16_rne((float)((p.x >> (2 * j)) & 3) * s + z);
        r.u[4 + j] = bf16_rne((float)((p.y >> (2 * j)) & 3) * s + z);
    }
    ((short8*)wb)[i] = r.v;
}

// ---------------- 128x128 BK=32 GEMM, 4 blocks/CU (R9) ----------------
// C[M][N] = A[M][K](bf16) * B[N][K](bf16)^T + bias.
// R9 theory: R7's 1-block/CU 8-wave structure serializes the per-phase LDS
// window vs MFMA window. Flip to INTER-BLOCK overlap (m114): 256 thr (4
// waves, 2Mx2N, wave=64x64), <=128 regs/wave (launch_bounds(256,4)) ->
// 16 waves/CU = 4 co-resident blocks; one block's MFMA hides another's
// LDS/barrier window. LDS 32KB/block (2 bufs x (A 8KB + B 8KB)).
//
// SYNC LEDGER (R6-proven free-run shape; buf d = t&1):
//  reads(8 b128) -> 16 MFMA  (data-dep: reads returned before last MFMA)
//  B1: cross-wave, buf d free
//  stage tile t+2 -> buf d (4 gloads; disjoint from buf d^1 read next)
//  vmcnt(4): outstanding = t+1's 4 + t+2's 4 -> drains t+1 fully
//  B2: tile t+1 resident cross-wave
//  tail: t+2 clamped to t => byte-idempotent restage; post-loop vmcnt(0).
// Swizzle (64B rows, both-sides): LDS(r, 8j) = G(r, 8*(j ^ (r&3))), j=0..3;
//  read seg = lk4 ^ (lr&3). Bank check: quad q = 4*(lr&1) + (lk4^(lr&3));
//  8 lanes/quad x 16B = 128B over 8 cy = quad BW -> conflict-free.

#define WGBAR \
    __builtin_amdgcn_sched_barrier(0); \
    __builtin_amdgcn_s_barrier(); \
    __builtin_amdgcn_sched_barrier(0);

__global__ __launch_bounds__(256, 4) void gemm128(const unsigned short* __restrict__ A,
                                                  const unsigned short* __restrict__ B,
                                                  const float* __restrict__ bias,
                                                  float* __restrict__ C) {
    __shared__ __align__(16) unsigned short sm[16384];   // 32 KiB: buf d @ d*8192 (A 4096 + B 4096 shorts)

    const int tid = threadIdx.x;
    const int w = tid >> 6;              // wave 0..3
    const int lane = tid & 63;

    // T1: bijective XCD swizzle (gridDim.x % 8 == 0)
    const int nwg = gridDim.x;
    const int chunk = nwg >> 3;
    const int s_id = (blockIdx.x & 7) * chunk + (blockIdx.x >> 3);
    const int nm = 64;                   // M tiles (8192/128); N tiles = 32
    const int bm = s_id % nm;
    const int bn = s_id / nm;
    const int row0 = bm * 128;
    const int col0 = bn * 128;

    const int wm = w >> 1;               // 0..1 (M half: 64 rows)
    const int wn = w & 1;                // 0..1 (N half: 64 cols)

    // ---- stage addressing: slot = tid (+256); row = slot>>2, seg = slot&3
    const int srow = tid >> 2;                                  // 0..63
    const int sswz = 8 * ((tid & 3) ^ ((tid >> 2) & 3));        // pre-swizzled src elem offset
    const unsigned short* srcA = A + (size_t)(row0 + srow) * KDIM + sswz;
    const unsigned short* srcB = B + (size_t)(col0 + srow) * KDIM + sswz;
    // +64 rows for second gload: row&3 unchanged (64 % 4 == 0) -> same swizzle ✓

    // ---- frag addressing: row = wX*64 + m*16 + lr; seg = lk4 ^ (lr&3)
    const int lr = lane & 15;
    const int lk4 = lane >> 4;
    const int fsw = 8 * (lk4 ^ (lr & 3));
    const int aBase = (wm * 64 + lr) * 32 + fsw;          // + m*512
    const int bBase = 4096 + (wn * 64 + lr) * 32 + fsw;   // + n*512

    f32x4 acc[4][4] = {};
    short8 aF[4], bF[4];

    auto stage = [&](int tile, int db) {
        const int dOff = db * 8192;
        const unsigned short* gA = srcA + (size_t)tile * 32;
        const unsigned short* gB = srcB + (size_t)tile * 32;
        gload_lds16(gA, &sm[dOff + w * 512]);                    // A rows 0-63
        gload_lds16(gA + (size_t)64 * KDIM, &sm[dOff + 2048 + w * 512]);   // A rows 64-127
        gload_lds16(gB, &sm[dOff + 4096 + w * 512]);             // B rows 0-63
        gload_lds16(gB + (size_t)64 * KDIM, &sm[dOff + 6144 + w * 512]);   // B rows 64-127
    };

    const int NT = KDIM / 32;   // 128 K-tiles

    // ---- prologue: tile0 -> buf0, tile1 -> buf1
    stage(0, 0);
    stage(1, 1);
    __builtin_amdgcn_sched_barrier(0);
    asm volatile("s_waitcnt vmcnt(4)" ::: "memory");   // tile0 resident (tile1 in flight)
    WGBAR

    for (int t = 0; t < NT; ++t) {
        const int d = t & 1;
        const int dOff = d * 8192;
        const int t2 = (t + 2 < NT) ? t + 2 : t;   // clamped tail: byte-idempotent restage

        // ---- reads (8 x ds_read_b128), then MFMA (compiler inserts lgkmcnt) ----
#pragma unroll
        for (int m = 0; m < 4; ++m)
            aF[m] = *(const short8*)&sm[dOff + aBase + m * 512];
#pragma unroll
        for (int n = 0; n < 4; ++n)
            bF[n] = *(const short8*)&sm[dOff + bBase + n * 512];

        __builtin_amdgcn_s_setprio(1);
#pragma unroll
        for (int m = 0; m < 4; ++m)
#pragma unroll
            for (int n = 0; n < 4; ++n)
                acc[m][n] = __builtin_amdgcn_mfma_f32_16x16x32_bf16(
                    __builtin_bit_cast(bf16x8, aF[m]),
                    __builtin_bit_cast(bf16x8, bF[n]),
                    acc[m][n], 0, 0, 0);
        __builtin_amdgcn_s_setprio(0);

        // ---- B1: all reads of tile t done (data-dep) -> buf d free ----
        WGBAR
        stage(t2, d);
        __builtin_amdgcn_sched_barrier(0);
        asm volatile("s_waitcnt vmcnt(4)" ::: "memory");   // drain tile t+1's loads
        __builtin_amdgcn_sched_barrier(0);
        // ---- B2: tile t+1 resident cross-wave ----
        WGBAR
    }

    // no LDS-DMA may outlive the loop
    __builtin_amdgcn_sched_barrier(0);
    asm volatile("s_waitcnt vmcnt(0)" ::: "memory");
    __builtin_amdgcn_sched_barrier(0);

    // ---- epilogue: C/D layout col=lane&15, row=(lane>>4)*4+r
#pragma unroll
    for (int m = 0; m < 4; ++m) {
#pragma unroll
        for (int n = 0; n < 4; ++n) {
            int col = col0 + wn * 64 + n * 16 + lr;
            float bz = bias[col];
#pragma unroll
            for (int r = 0; r < 4; ++r) {
                int row = row0 + wm * 64 + m * 16 + lk4 * 4 + r;
                C[(size_t)row * NDIM + col] = acc[m][n][r] + bz;
            }
        }
    }
}

// ---------------- emergency fallback (ws too small / odd shape): exact fp32 ----------------
__global__ void fallback_kernel(const float* __restrict__ x, const int* __restrict__ wp,
                                const float* __restrict__ scales, const float* __restrict__ zeros,
                                const float* __restrict__ bias, float* __restrict__ out) {
    int o = blockIdx.x * 256 + threadIdx.x;
    int m = blockIdx.y;
    __shared__ float xs[KDIM];
    for (int i = threadIdx.x; i < KDIM; i += 256) xs[i] = x[(size_t)m * KDIM + i];
    __syncthreads();
    float acc = 0.f;
    for (int g = 0; g < 32; ++g) {
        float s = scales[o * 32 + g], z = zeros[o * 32 + g];
        float aq = 0.f, ax = 0.f;
        for (int j = 0; j < 32; ++j) {
            int p = wp[o * 1024 + g * 32 + j];
            int kb = g * 128 + j * 4;
#pragma unroll
            for (int q = 0; q < 4; ++q) {
                float xv = xs[kb + q];
                aq += xv * (float)((p >> (2 * q)) & 3);
                ax += xv;
            }
        }
        acc += s * aq + z * ax;
    }
    out[(size_t)m * NDIM + o] = acc + bias[o];
}

extern "C" void kernel_launch(void* const* d_in, const int* in_sizes, int n_in,
                              void* d_out, int out_size, void* d_ws, size_t ws_size,
                              hipStream_t stream) {
    const float* x      = (const float*)d_in[0];
    const int*   wp     = (const int*)d_in[1];
    const float* scales = (const float*)d_in[2];
    const float* zeros  = (const float*)d_in[3];
    const float* bias   = (const float*)d_in[4];
    float* out = (float*)d_out;

    const long M = (long)in_sizes[0] / KDIM;            // 8192
    const long PACKED = (long)in_sizes[1];              // 4194304
    const size_t need = (size_t)M * KDIM * 2 + (size_t)NDIM * KDIM * 2;  // 96 MB

    if (ws_size >= need && (M % 128) == 0) {
        unsigned short* xb = (unsigned short*)d_ws;
        unsigned short* wb = xb + (size_t)M * KDIM;
        cvt_x_kernel<<<(M * KDIM / 8) / 256, 256, 0, stream>>>(x, xb);
        dequant_w_kernel<<<(PACKED / 2) / 256, 256, 0, stream>>>(wp, scales, zeros, wb);
        int nwg = (int)(M / 128) * (NDIM / 128);        // 64*32 = 2048, %8==0
        gemm128<<<nwg, 256, 0, stream>>>(xb, wb, bias, out);
    } else {
        dim3 grid(NDIM / 256, M);
        fallback_kernel<<<grid, 256, 0, stream>>>(x, wp, scales, zeros, bias, out);
    }
}

// Round 10
// 285.425 us; speedup vs baseline: 1.9408x; 1.4355x over previous
//
#include <hip/hip_runtime.h>
#include <hip/hip_bf16.h>
#include <cstdint>
#include <cstddef>

#define KDIM 4096   // IN_F
#define NDIM 4096   // OUT_F

typedef __attribute__((ext_vector_type(8))) short short8;
typedef __attribute__((ext_vector_type(8))) __bf16 bf16x8;
typedef __attribute__((ext_vector_type(4))) float f32x4;

// f32 -> bf16, round-to-nearest-even
__device__ __forceinline__ unsigned short bf16_rne(float f) {
    unsigned int u = __builtin_bit_cast(unsigned int, f);
    u += 0x7fffu + ((u >> 16) & 1u);
    return (unsigned short)(u >> 16);
}

__device__ __forceinline__ void gload_lds16(const unsigned short* g, unsigned short* l) {
    __builtin_amdgcn_global_load_lds(
        (const __attribute__((address_space(1))) unsigned int*)g,
        (__attribute__((address_space(3))) unsigned int*)l,
        16, 0, 0);
}

// ---------------- preprocess: x fp32 -> bf16 ----------------
__global__ void cvt_x_kernel(const float* __restrict__ x, unsigned short* __restrict__ xb) {
    long i = (long)blockIdx.x * blockDim.x + threadIdx.x;   // one thread = 8 elems
    float4 a = ((const float4*)x)[2 * i];
    float4 b = ((const float4*)x)[2 * i + 1];
    union { unsigned short u[8]; short8 v; } r;
    r.u[0] = bf16_rne(a.x); r.u[1] = bf16_rne(a.y);
    r.u[2] = bf16_rne(a.z); r.u[3] = bf16_rne(a.w);
    r.u[4] = bf16_rne(b.x); r.u[5] = bf16_rne(b.y);
    r.u[6] = bf16_rne(b.z); r.u[7] = bf16_rne(b.w);
    ((short8*)xb)[i] = r.v;
}

// ---------------- preprocess: dequant 2-bit W -> bf16 [N][K] ----------------
__global__ void dequant_w_kernel(const int* __restrict__ wp,
                                 const float* __restrict__ scales,
                                 const float* __restrict__ zeros,
                                 unsigned short* __restrict__ wb) {
    long i = (long)blockIdx.x * blockDim.x + threadIdx.x;   // one thread = 2 packed ints = 8 weights
    int2 p = ((const int2*)wp)[i];
    long base = i * 8;                    // flat weight index (o*4096 + k)
    int o = (int)(base >> 12);
    int g = (int)((base & 4095) >> 7);    // all 8 weights in same group (8 | 128)
    float s = scales[o * 32 + g];
    float z = zeros[o * 32 + g];
    union { unsigned short u[8]; short8 v; } r;
#pragma unroll
    for (int j = 0; j < 4; ++j) {
        r.u[j]     = bf16_rne((float)((p.x >> (2 * j)) & 3) * s + z);
        r.u[4 + j] = bf16_rne((float)((p.y >> (2 * j)) & 3) * s + z);
    }
    ((short8*)wb)[i] = r.v;
}

// ---------------- 256x256 3-phase GEMM (R10) ----------------
// C[M][N] = A[M][K](bf16) * B[N][K](bf16)^T + bias.
// R10 = R7 with two surgical changes:
//  (1) NO explicit lgkmcnt(0) before MFMA. The ds_reads are plain C++ loads;
//      the compiler emits fine-grained lgkmcnt(N) per use (m97-verified), so
//      MFMA starts after the FIRST fragment returns and the remaining reads
//      drain UNDER the MFMA cluster. (Explicit drain is only required for
//      inline-asm ds_reads — rule 18 — which we don't use.)
//  (2) Read-less P4 merged into P3 -> 3 phases/tile, 6 barriers (was 8).
// Phase = { ds_reads | stages | [vmcnt] | SB+s_barrier | setprio1 16/32 MFMA
//           setprio0 | SB+s_barrier }.  SB at barriers pins the epoch (no
// read/MFMA sinks past a barrier); inside the phase the compiler is free.
//
// REGION LEDGER (iter i: tile e=2i buf0@0, o=2i+1 buf1@32768):
//  reads: e.Ph1 aF=A-h0(e)+bQ0=B01(e); e.Ph2 bQ1=B23(e); e.Ph3 aG=A-h1(e);
//         (mirror for o). Every read is consumed by its OWN phase's MFMA
//         cluster (data-dep => returned before phase-end barrier).
//  frees: buf0.B after e.Ph2-end; buf0.A after e.Ph3-end;
//         buf1.B after o.Ph2-end; buf1.A after o.Ph3-end.
//  stage ring: e.Ph1: A0(o)->buf1.A   [buf1.A free since (i-1).o.Ph3]
//              e.Ph2: A1(o)->buf1.A   [same]
//              e.Ph3: B0(e+2),B1(e+2)->buf0.B [buf0.B free after e.Ph2-end]
//              o.Ph1: A0(e+2)->buf0.A [buf0.A free after e.Ph3-end]
//              o.Ph2: A1(e+2)->buf0.A
//              o.Ph3: B0(o+2),B1(o+2)->buf1.B [buf1.B free after o.Ph2-end]
//  VMCNT(4)@e.Ph3 (after its 2 stages): in-flight 12 = B(o)4[(i-1).o.Ph3] +
//   A0(o)2 + A1(o)2 + B(e+2)4; drains 8 oldest => buf1(o) FULLY resident
//   before o.Ph1; barrier => cross-wave.
//  VMCNT(4)@o.Ph3: in-flight 12 = B(e+2)4 + A0(e+2)2 + A1(e+2)2 + B(o+2)4;
//   drains 8 => buf0(e+2) resident before (i+1).e.Ph1.
//  prologue: B(0),A(0)->buf0 (8), B(1)->buf1 (4); vmcnt(4) => buf0 resident.
//  tail: e2/o2 clamped => byte-idempotent restage; post-loop vmcnt(0).
// Swizzle (proven, 0 conflicts): LDS(r,8j)=G(r,8*(j^(r&7))); read elem
//  R*64 + 8*((4s+lk4)^(R&7)), R&7 == lane&7.

#define PH_BAR \
    __builtin_amdgcn_sched_barrier(0); \
    __builtin_amdgcn_s_barrier();

#define VMCNT4 \
    __builtin_amdgcn_sched_barrier(0); \
    asm volatile("s_waitcnt vmcnt(4)" ::: "memory"); \
    __builtin_amdgcn_sched_barrier(0);

#define RD_A(arr, DOFF, mh) \
    _Pragma("unroll") \
    for (int mi_ = 0; mi_ < 4; ++mi_) { \
        arr[mi_][0] = *(const short8*)&sm[(DOFF) + aBase + ((mh)*4 + mi_) * 1024 + sw0]; \
        arr[mi_][1] = *(const short8*)&sm[(DOFF) + aBase + ((mh)*4 + mi_) * 1024 + sw1]; \
    }

#define RD_B(bx, DOFF, n0) \
    _Pragma("unroll") \
    for (int ni_ = 0; ni_ < 2; ++ni_) { \
        bx[ni_][0] = *(const short8*)&sm[(DOFF) + bBase + ((n0) + ni_) * 1024 + sw0]; \
        bx[ni_][1] = *(const short8*)&sm[(DOFF) + bBase + ((n0) + ni_) * 1024 + sw1]; \
    }

#define QUADX(af, bx, mh, nh) \
    _Pragma("unroll") \
    for (int s_ = 0; s_ < 2; ++s_) { \
      _Pragma("unroll") \
      for (int mi_ = 0; mi_ < 4; ++mi_) { \
        _Pragma("unroll") \
        for (int ni_ = 0; ni_ < 2; ++ni_) { \
          acc[(mh)*4+mi_][(nh)*2+ni_] = __builtin_amdgcn_mfma_f32_16x16x32_bf16( \
            __builtin_bit_cast(bf16x8, af[mi_][s_]), \
            __builtin_bit_cast(bf16x8, bx[ni_][s_]), \
            acc[(mh)*4+mi_][(nh)*2+ni_], 0, 0, 0); \
        } } }

__global__ __launch_bounds__(512, 2) void gemm256(const unsigned short* __restrict__ A,
                                                  const unsigned short* __restrict__ B,
                                                  const float* __restrict__ bias,
                                                  float* __restrict__ C) {
    __shared__ __align__(16) unsigned short sm[65536];   // 128 KiB

    const int tid = threadIdx.x;
    const int w64 = tid >> 6;
    const int lane = tid & 63;

    // T1: bijective XCD swizzle (gridDim.x % 8 == 0)
    const int nwg = gridDim.x;
    const int chunk = nwg >> 3;
    const int s_id = (blockIdx.x & 7) * chunk + (blockIdx.x >> 3);
    const int nm = nwg >> 4;              // M tiles (N tiles fixed at 16)
    const int bm = s_id % nm;
    const int bn = s_id / nm;
    const int row0 = bm * 256;
    const int col0 = bn * 256;

    const int wr = w64 >> 2;              // 0..1 (M half: 128 rows)
    const int wc = w64 & 3;               // 0..3 (N quarter: 64 cols)

    // ---- stage addressing (proven): row srow(+64,+128h), swizzled k
    const int srow = tid >> 3;                                  // 0..63
    const int swzk = 8 * ((tid & 7) ^ ((tid >> 3) & 7));        // pre-swizzled src elem
    const unsigned short* srcA = A + (size_t)(row0 + srow) * KDIM + swzk;
    const unsigned short* srcB = B + (size_t)(col0 + srow) * KDIM + swzk;

    // ---- frag addressing (proven, 0 conflicts)
    const int lr = lane & 15;
    const int lk4 = lane >> 4;
    const int l7 = lane & 7;
    const int sw0 = 8 * (((0 << 2) + lk4) ^ l7);
    const int sw1 = 8 * (((1 << 2) + lk4) ^ l7);
    const int aBase = (wr * 128 + lr) * 64;
    const int bBase = 16384 + (wc * 64 + lr) * 64;

    f32x4 acc[8][4] = {};
    short8 aF[4][2], aG[4][2], bQ0[2][2], bQ1[2][2];

    auto stageA = [&](int hh, int tile, int db) {
        const unsigned short* g = srcA + (size_t)hh * 128 * KDIM + (size_t)tile * 64;
        unsigned short* l = &sm[db * 32768 + hh * 8192 + w64 * 512];
        gload_lds16(g, l);
        gload_lds16(g + (size_t)64 * KDIM, l + 4096);
    };
    auto stageB = [&](int hh, int tile, int db) {
        const unsigned short* g = srcB + (size_t)hh * 128 * KDIM + (size_t)tile * 64;
        unsigned short* l = &sm[db * 32768 + 16384 + hh * 8192 + w64 * 512];
        gload_lds16(g, l);
        gload_lds16(g + (size_t)64 * KDIM, l + 4096);
    };

    const int NT = KDIM / 64;   // 64 K-tiles (even)

    // ---- prologue: tile0 -> buf0 (8 loads), tile1.B -> buf1 (4 loads)
    stageB(0, 0, 0); stageB(1, 0, 0); stageA(0, 0, 0); stageA(1, 0, 0);
    stageB(0, 1, 1); stageB(1, 1, 1);
    VMCNT4                      // buf0 fully resident; buf1.B still flying
    __builtin_amdgcn_s_barrier();

    for (int i = 0; i < NT / 2; ++i) {
        const int e = 2 * i;
        const int o = e + 1;
        const int e2 = (e + 2 < NT) ? e + 2 : e;   // clamp: byte-idempotent restage
        const int o2 = (o + 2 < NT) ? o + 2 : o;

        // ========== tile e (buf0 @0) ==========
        // Ph1: reads aF=A-h0, bQ0=B01; stage A0(o)->buf1
        RD_A(aF, 0, 0)
        RD_B(bQ0, 0, 0)
        stageA(0, o, 1);
        PH_BAR
        __builtin_amdgcn_s_setprio(1);
        QUADX(aF, bQ0, 0, 0)
        __builtin_amdgcn_s_setprio(0);
        PH_BAR
        // Ph2: reads bQ1=B23; stage A1(o)->buf1
        RD_B(bQ1, 0, 2)
        stageA(1, o, 1);
        PH_BAR
        __builtin_amdgcn_s_setprio(1);
        QUADX(aF, bQ1, 0, 1)
        __builtin_amdgcn_s_setprio(0);
        PH_BAR
        // Ph3: reads aG=A-h1; stage B0,B1(e+2)->buf0; vmcnt => buf1(o) resident
        RD_A(aG, 0, 1)
        stageB(0, e2, 0);
        stageB(1, e2, 0);
        VMCNT4
        PH_BAR
        __builtin_amdgcn_s_setprio(1);
        QUADX(aG, bQ0, 1, 0)
        QUADX(aG, bQ1, 1, 1)
        __builtin_amdgcn_s_setprio(0);
        PH_BAR

        // ========== tile o (buf1 @32768) ==========
        // Ph1: reads aF, bQ0; stage A0(e+2)->buf0
        RD_A(aF, 32768, 0)
        RD_B(bQ0, 32768, 0)
        stageA(0, e2, 0);
        PH_BAR
        __builtin_amdgcn_s_setprio(1);
        QUADX(aF, bQ0, 0, 0)
        __builtin_amdgcn_s_setprio(0);
        PH_BAR
        // Ph2: reads bQ1; stage A1(e+2)->buf0
        RD_B(bQ1, 32768, 2)
        stageA(1, e2, 0);
        PH_BAR
        __builtin_amdgcn_s_setprio(1);
        QUADX(aF, bQ1, 0, 1)
        __builtin_amdgcn_s_setprio(0);
        PH_BAR
        // Ph3: reads aG; stage B0,B1(o+2)->buf1; vmcnt => buf0(e+2) resident
        RD_A(aG, 32768, 1)
        stageB(0, o2, 1);
        stageB(1, o2, 1);
        VMCNT4
        PH_BAR
        __builtin_amdgcn_s_setprio(1);
        QUADX(aG, bQ0, 1, 0)
        QUADX(aG, bQ1, 1, 1)
        __builtin_amdgcn_s_setprio(0);
        PH_BAR
    }

    // no LDS-DMA / dangling reads may outlive the loop
    __builtin_amdgcn_sched_barrier(0);
    asm volatile("s_waitcnt vmcnt(0) lgkmcnt(0)" ::: "memory");
    __builtin_amdgcn_sched_barrier(0);

    // ---- epilogue: C/D layout col=lane&15, row=(lane>>4)*4+r
#pragma unroll
    for (int m = 0; m < 8; ++m) {
#pragma unroll
        for (int n = 0; n < 4; ++n) {
            int col = col0 + wc * 64 + n * 16 + lr;
            float bz = bias[col];
#pragma unroll
            for (int r = 0; r < 4; ++r) {
                int row = row0 + wr * 128 + m * 16 + lk4 * 4 + r;
                C[(size_t)row * NDIM + col] = acc[m][n][r] + bz;
            }
        }
    }
}

// ---------------- emergency fallback (ws too small / odd shape): exact fp32 ----------------
__global__ void fallback_kernel(const float* __restrict__ x, const int* __restrict__ wp,
                                const float* __restrict__ scales, const float* __restrict__ zeros,
                                const float* __restrict__ bias, float* __restrict__ out) {
    int o = blockIdx.x * 256 + threadIdx.x;
    int m = blockIdx.y;
    __shared__ float xs[KDIM];
    for (int i = threadIdx.x; i < KDIM; i += 256) xs[i] = x[(size_t)m * KDIM + i];
    __syncthreads();
    float acc = 0.f;
    for (int g = 0; g < 32; ++g) {
        float s = scales[o * 32 + g], z = zeros[o * 32 + g];
        float aq = 0.f, ax = 0.f;
        for (int j = 0; j < 32; ++j) {
            int p = wp[o * 1024 + g * 32 + j];
            int kb = g * 128 + j * 4;
#pragma unroll
            for (int q = 0; q < 4; ++q) {
                float xv = xs[kb + q];
                aq += xv * (float)((p >> (2 * q)) & 3);
                ax += xv;
            }
        }
        acc += s * aq + z * ax;
    }
    out[(size_t)m * NDIM + o] = acc + bias[o];
}

extern "C" void kernel_launch(void* const* d_in, const int* in_sizes, int n_in,
                              void* d_out, int out_size, void* d_ws, size_t ws_size,
                              hipStream_t stream) {
    const float* x      = (const float*)d_in[0];
    const int*   wp     = (const int*)d_in[1];
    const float* scales = (const float*)d_in[2];
    const float* zeros  = (const float*)d_in[3];
    const float* bias   = (const float*)d_in[4];
    float* out = (float*)d_out;

    const long M = (long)in_sizes[0] / KDIM;            // 8192
    const long PACKED = (long)in_sizes[1];              // 4194304
    const size_t need = (size_t)M * KDIM * 2 + (size_t)NDIM * KDIM * 2;  // 96 MB

    if (ws_size >= need && (M % 256) == 0) {
        unsigned short* xb = (unsigned short*)d_ws;
        unsigned short* wb = xb + (size_t)M * KDIM;
        cvt_x_kernel<<<(M * KDIM / 8) / 256, 256, 0, stream>>>(x, xb);
        dequant_w_kernel<<<(PACKED / 2) / 256, 256, 0, stream>>>(wp, scales, zeros, wb);
        int nwg = (int)(M / 256) * (NDIM / 256);        // 32*16 = 512, %8==0
        gemm256<<<nwg, 512, 0, stream>>>(xb, wb, bias, out);
    } else {
        dim3 grid(NDIM / 256, M);
        fallback_kernel<<<grid, 256, 0, stream>>>(x, wp, scales, zeros, bias, out);
    }
}